// Round 15
// baseline (104.738 us; speedup 1.0000x reference)
//
#include <hip/hip_runtime.h>
#include <math.h>

// Problem constants
#define BB 256
#define NE 400
#define NP (BB * NE)        // 102400 pairs
#define HID 256
#define NCOP 224
#define DIN 480
#define MBLK 64             // pairs per block in fused MFMA kernel
#define NBLK (NP / MBLK)    // 1600

typedef _Float16 half8 __attribute__((ext_vector_type(8)));
typedef _Float16 half4 __attribute__((ext_vector_type(4)));
typedef float f4 __attribute__((ext_vector_type(4)));

// Native silu: v_mul + v_exp_f32 + v_add + v_rcp_f32 + v_mul (round 13: -12 us).
static __device__ __forceinline__ float silu_f(float x) {
    float e = __builtin_amdgcn_exp2f(x * -1.44269504088896340736f);
    return x * __builtin_amdgcn_rcpf(1.0f + e);
}

// LDS-only barrier: drain lgkmcnt (ds ops) but let vmcnt (global prefetches)
// stay in flight across the barrier. __syncthreads() would emit
// s_waitcnt vmcnt(0) and drain the weight prefetches (round 14's failure).
// All cross-thread data in this kernel flows through LDS, so lgkmcnt(0)
// is sufficient for correctness; sched_barrier(0) pins ordering (rule #18).
static __device__ __forceinline__ void barrier_lds() {
    __builtin_amdgcn_sched_barrier(0);
    asm volatile("s_waitcnt lgkmcnt(0)" ::: "memory");
    __builtin_amdgcn_s_barrier();
    __builtin_amdgcn_sched_barrier(0);
}

// Swizzled byte offset into the activation LDS buffer.
static __device__ __forceinline__ int swz(int row, int colbyte) {
    return (row * 512 + colbyte) ^ ((row & 7) << 4);
}

// ---------------------------------------------------------------------------
// Precompute (fp32): E1/F1/Fo/S as before.
// ---------------------------------------------------------------------------
__global__ void precompute_kernel(const float* __restrict__ h_abs,
                                  const float* __restrict__ e_feat,
                                  const float* __restrict__ field,
                                  const float* __restrict__ mW1,
                                  const float* __restrict__ mb1,
                                  const float* __restrict__ oW1,
                                  const float* __restrict__ ob1,
                                  float* __restrict__ E1,
                                  float* __restrict__ F1,
                                  float* __restrict__ Fo,
                                  float* __restrict__ S)
{
    int r = blockIdx.x;
    int t = threadIdx.x;
    if (r < NE) {
        float a = 0.f;
        #pragma unroll
        for (int k = 0; k < 32; ++k) a += e_feat[r * 32 + k] * mW1[k * HID + t];
        E1[r * HID + t] = a;
    } else if (r < NE + BB) {
        int b = r - NE;
        float a = mb1[t];
        #pragma unroll
        for (int k = 0; k < 64; ++k) a += field[b * 64 + k] * mW1[(32 + k) * HID + t];
        F1[b * HID + t] = a;
    } else if (r < NE + 2 * BB) {
        int b = r - NE - BB;
        float a = ob1[t];
        #pragma unroll
        for (int k = 0; k < 64; ++k) a += field[b * 64 + k] * oW1[(224 + k) * HID + t];
        Fo[b * HID + t] = a;
    } else {
        int b = r - NE - 2 * BB;
        if (t < 64) {
            const float* x = h_abs + b * DIN + 128 + t * 3;
            S[b * 96 + t] = (x[0]*x[0] + x[1]*x[1] + x[2]*x[2]) * (1.0f / 3.0f);
        } else if (t < 96) {
            int c = t - 64;
            const float* x = h_abs + b * DIN + 320 + c * 5;
            float s = 0.f;
            #pragma unroll
            for (int d = 0; d < 5; ++d) s += x[d] * x[d];
            S[b * 96 + t] = s * 0.2f;
        }
    }
}

// ---------------------------------------------------------------------------
// Pack weights (fp32 -> fp16) into MFMA A-operand fragment order.
// ---------------------------------------------------------------------------
__global__ void pack_weights(const float* __restrict__ mW2, const float* __restrict__ mW3,
                             const float* __restrict__ oW1, const float* __restrict__ oW2,
                             _Float16* __restrict__ PB2, _Float16* __restrict__ PB3,
                             _Float16* __restrict__ PO1, _Float16* __restrict__ PO2)
{
    int blk = blockIdx.x;
    int l = threadIdx.x;
    const float* W; _Float16* P; int LD;
    if (blk < 128)      { W = mW2; P = PB2; LD = 256; }
    else if (blk < 240) { blk -= 128; W = mW3; P = PB3; LD = 224; }
    else if (blk < 352) { blk -= 240; W = oW1; P = PO1; LD = 256; }
    else                { blk -= 352; W = oW2; P = PO2; LD = 256; }
    int KST = (P == PO1) ? 7 : 8;
    int nt = blk / KST, ks = blk - nt * KST;
    int n  = nt * 16 + (l & 15);
    int k0 = ks * 32 + (l >> 4) * 8;
    half8 v;
    #pragma unroll
    for (int j = 0; j < 8; ++j) v[j] = (_Float16)W[(size_t)(k0 + j) * LD + n];
    *(half8*)&P[(size_t)(blk * 64 + l) * 8] = v;
}

// ---------------------------------------------------------------------------
// Split GEMM phase: load_frags issues the L2 weight loads (now genuinely
// in flight across barrier_lds); mma_compute consumes them after the barrier.
// ---------------------------------------------------------------------------
template<int KST, bool TWO>
static __device__ __forceinline__ void load_frags(const half8* __restrict__ Wp,
                                                  int lane, int tile0,
                                                  half8 f0[], half8 f1[])
{
    #pragma unroll
    for (int ks = 0; ks < KST; ++ks)
        f0[ks] = Wp[(tile0 * KST + ks) * 64 + lane];
    if (TWO) {
        #pragma unroll
        for (int ks = 0; ks < KST; ++ks)
            f1[ks] = Wp[((tile0 + 8) * KST + ks) * 64 + lane];
    }
}

template<int KST, bool TWO>
static __device__ __forceinline__ void mma_compute(const half8 f0[], const half8 f1[],
                                                   const char* actp, int lane,
                                                   f4 acc[4][2])
{
    #pragma unroll
    for (int mt = 0; mt < 4; ++mt) {
        acc[mt][0] = (f4){0.f, 0.f, 0.f, 0.f};
        acc[mt][1] = (f4){0.f, 0.f, 0.f, 0.f};
    }
    #pragma unroll
    for (int ks = 0; ks < KST; ++ks) {
        int kb = ks * 64 + ((lane >> 4) << 4);
        half8 a[4];
        #pragma unroll
        for (int mt = 0; mt < 4; ++mt) {
            int row = mt * 16 + (lane & 15);
            a[mt] = *(const half8*)(actp + ((row * 512 + kb) ^ ((row & 7) << 4)));
        }
        #pragma unroll
        for (int mt = 0; mt < 4; ++mt)
            acc[mt][0] = __builtin_amdgcn_mfma_f32_16x16x32_f16(f0[ks], a[mt], acc[mt][0], 0, 0, 0);
        if (TWO) {
            #pragma unroll
            for (int mt = 0; mt < 4; ++mt)
                acc[mt][1] = __builtin_amdgcn_mfma_f32_16x16x32_f16(f1[ks], a[mt], acc[mt][1], 0, 0, 0);
        }
    }
}

// ---------------------------------------------------------------------------
// Fused kernel: 64 pairs / block, 512 threads (8 waves).
// Weight fragments + epilogue operands prefetched across LDS-only barriers.
// ---------------------------------------------------------------------------
__global__ __launch_bounds__(512, 1)
void fused_mfma(const float* __restrict__ h_abs,
                const float* __restrict__ mb2, const float* __restrict__ mb3,
                const float* __restrict__ ob2,
                const float* __restrict__ oW3, const float* __restrict__ ob3,
                const float* __restrict__ E1, const float* __restrict__ F1,
                const float* __restrict__ Fo, const float* __restrict__ S,
                const half8* __restrict__ PB2, const half8* __restrict__ PB3,
                const half8* __restrict__ PO1, const half8* __restrict__ PO2,
                float* __restrict__ out)
{
    __shared__ char act[MBLK * 512];   // 32 KB f16 activations [64][256]
    __shared__ float sred[8][64];      // cross-wave partial sums

    const int t    = threadIdx.x;
    const int lane = t & 63;
    const int w    = t >> 6;           // 0..7
    const int p0   = blockIdx.x * MBLK;
    const int lr   = lane & 15;
    const int lq   = lane >> 4;

    const int b0 = p0 / NE;
    const int r0 = p0 - b0 * NE;

    // Prefetch phase-B weight fragments (consumed after the first barrier).
    half8 fb0[8], fb1[8];
    load_frags<8, true>(PB2, lane, w, fb0, fb1);

    // ---- Phase A: h1 = silu(E1[e] + F1[b])  -> act (f16) ----
    {
        #pragma unroll
        for (int i = 0; i < 4; ++i) {
            int c   = i * 512 + t;
            int row = c >> 5;
            int c0  = (c & 31) * 8;
            int e = r0 + row;
            int b = b0;
            if (e >= NE) { e -= NE; b += 1; }
            const f4* ep = (const f4*)&E1[e * HID + c0];
            const f4* fp = (const f4*)&F1[b * HID + c0];
            f4 e0 = ep[0], e1 = ep[1];
            f4 f0 = fp[0], f1 = fp[1];
            half8 hv;
            #pragma unroll
            for (int j = 0; j < 4; ++j) hv[j]     = (_Float16)silu_f(e0[j] + f0[j]);
            #pragma unroll
            for (int j = 0; j < 4; ++j) hv[4 + j] = (_Float16)silu_f(e1[j] + f1[j]);
            *(half8*)(act + swz(row, c0 * 2)) = hv;
        }
    }
    barrier_lds();

    f4 acc[4][2];

    // ---- Phase B: h2 = silu(h1 @ mW2 + mb2)  [in-place] ----
    mma_compute<8, true>(fb0, fb1, act, lane, acc);
    // Prefetch phase-C fragments; they stay in flight across the barriers.
    half8 fc0[8], fc1[8];
    if (w < 6) load_frags<8, true >(PB3, lane, w, fc0, fc1);
    else       load_frags<8, false>(PB3, lane, w, fc0, fc1);
    barrier_lds();   // all reads of h1 done
    #pragma unroll
    for (int ntj = 0; ntj < 2; ++ntj) {
        int n0 = (w + ntj * 8) * 16 + lq * 4;
        f4 bias = *(const f4*)&mb2[n0];
        #pragma unroll
        for (int mt = 0; mt < 4; ++mt) {
            int row = mt * 16 + lr;
            half4 hv;
            #pragma unroll
            for (int r = 0; r < 4; ++r)
                hv[r] = (_Float16)silu_f(acc[mt][ntj][r] + bias[r]);
            *(half4*)(act + swz(row, n0 * 2)) = hv;
        }
    }
    barrier_lds();   // h2 visible

    // ---- Phase C: g = h2 @ mW3 + mb3 ; invariant  [in-place] ----
    if (w < 6) mma_compute<8, true >(fc0, fc1, act, lane, acc);
    else       mma_compute<8, false>(fc0, fc1, act, lane, acc);
    // Prefetch phase-D fragments + C-epilogue operands during C epilogue.
    half8 fd0[7], fd1[7];
    load_frags<7, true>(PO1, lane, w, fd0, fd1);
    int bmt[4];
    #pragma unroll
    for (int mt = 0; mt < 4; ++mt)
        bmt[mt] = b0 + ((r0 + mt * 16 + lr) >= NE);
    f4 xh[4], sv[4];
    {
        int nc = w * 16 + lq * 4;
        #pragma unroll
        for (int mt = 0; mt < 4; ++mt)
            xh[mt] = *(const f4*)&h_abs[bmt[mt] * DIN + nc];
        if (w < 6) {
            #pragma unroll
            for (int mt = 0; mt < 4; ++mt)
                sv[mt] = *(const f4*)&S[bmt[mt] * 96 + nc];
        }
    }
    barrier_lds();
    {
        // ntj=0: tile w (<8) -> scalar passthrough path, always.
        int n0 = w * 16 + lq * 4;
        f4 bias = *(const f4*)&mb3[n0];
        #pragma unroll
        for (int mt = 0; mt < 4; ++mt) {
            int row = mt * 16 + lr;
            half4 hv;
            #pragma unroll
            for (int r = 0; r < 4; ++r)
                hv[r] = (_Float16)(xh[mt][r] * (acc[mt][0][r] + bias[r]));
            *(half4*)(act + swz(row, n0 * 2)) = hv;
        }
        // ntj=1: tile w+8 (>=8, <14 iff w<6) -> L2-norm path.
        if (w < 6) {
            int n1 = (w + 8) * 16 + lq * 4;
            f4 bias1 = *(const f4*)&mb3[n1];
            #pragma unroll
            for (int mt = 0; mt < 4; ++mt) {
                int row = mt * 16 + lr;
                half4 hv;
                #pragma unroll
                for (int r = 0; r < 4; ++r) {
                    float g = acc[mt][1][r] + bias1[r];
                    hv[r] = (_Float16)__builtin_amdgcn_sqrtf(g * g * sv[mt][r] + 1e-8f);
                }
                *(half4*)(act + swz(row, n1 * 2)) = hv;
            }
        }
    }
    barrier_lds();

    // ---- Phase D: o1 = silu(inv @ oW1[0:224] + Fo[b])  [in-place] ----
    mma_compute<7, true>(fd0, fd1, act, lane, acc);
    // Prefetch phase-E fragments + Fo operands during D epilogue.
    half8 fe0[8], fe1[8];
    load_frags<8, true>(PO2, lane, w, fe0, fe1);
    f4 fo[4][2];
    #pragma unroll
    for (int mt = 0; mt < 4; ++mt)
        #pragma unroll
        for (int ntj = 0; ntj < 2; ++ntj)
            fo[mt][ntj] = *(const f4*)&Fo[bmt[mt] * HID + (w + ntj * 8) * 16 + lq * 4];
    barrier_lds();
    #pragma unroll
    for (int ntj = 0; ntj < 2; ++ntj) {
        int n0 = (w + ntj * 8) * 16 + lq * 4;
        #pragma unroll
        for (int mt = 0; mt < 4; ++mt) {
            int row = mt * 16 + lr;
            half4 hv;
            #pragma unroll
            for (int r = 0; r < 4; ++r)
                hv[r] = (_Float16)silu_f(acc[mt][ntj][r] + fo[mt][ntj][r]);
            *(half4*)(act + swz(row, n0 * 2)) = hv;
        }
    }
    barrier_lds();

    // ---- Phase E+F fused: out[p] = silu(o1 @ oW2 + ob2) . oW3 + ob3 ----
    mma_compute<8, true>(fe0, fe1, act, lane, acc);
    {
        float partial[4] = {0.f, 0.f, 0.f, 0.f};
        #pragma unroll
        for (int ntj = 0; ntj < 2; ++ntj) {
            int n0 = (w + ntj * 8) * 16 + lq * 4;
            f4 bias = *(const f4*)&ob2[n0];
            f4 wv   = *(const f4*)&oW3[n0];
            #pragma unroll
            for (int mt = 0; mt < 4; ++mt)
                #pragma unroll
                for (int r = 0; r < 4; ++r)
                    partial[mt] += silu_f(acc[mt][ntj][r] + bias[r]) * wv[r];
        }
        #pragma unroll
        for (int mt = 0; mt < 4; ++mt) {
            float s = partial[mt];
            s += __shfl_xor(s, 16, 64);
            s += __shfl_xor(s, 32, 64);
            if (lq == 0) sred[w][mt * 16 + lr] = s;
        }
    }
    barrier_lds();
    if (t < 64) {
        float s = ob3[0];
        #pragma unroll
        for (int ww = 0; ww < 8; ++ww) s += sred[ww][t];
        out[p0 + t] = s;
    }
}

extern "C" void kernel_launch(void* const* d_in, const int* in_sizes, int n_in,
                              void* d_out, int out_size, void* d_ws, size_t ws_size,
                              hipStream_t stream) {
    const float* h_abs  = (const float*)d_in[0];
    const float* e_feat = (const float*)d_in[1];
    const float* field  = (const float*)d_in[2];
    const float* mW1 = (const float*)d_in[3];
    const float* mb1 = (const float*)d_in[4];
    const float* mW2 = (const float*)d_in[5];
    const float* mb2 = (const float*)d_in[6];
    const float* mW3 = (const float*)d_in[7];
    const float* mb3 = (const float*)d_in[8];
    const float* oW1 = (const float*)d_in[9];
    const float* ob1 = (const float*)d_in[10];
    const float* oW2 = (const float*)d_in[11];
    const float* ob2 = (const float*)d_in[12];
    const float* oW3 = (const float*)d_in[13];
    const float* ob3 = (const float*)d_in[14];
    float* out = (float*)d_out;

    // Workspace layout
    float* ws = (float*)d_ws;
    float* E1 = ws;                      // 400*256 = 102400 f
    float* F1 = E1 + NE * HID;           // 65536 f
    float* Fo = F1 + BB * HID;           // 65536 f
    float* S  = Fo + BB * HID;           // 24576 f
    _Float16* PB2 = (_Float16*)(S + BB * 96);   // 16*8*64*8 = 65536 h
    _Float16* PB3 = PB2 + 16 * 8 * 64 * 8;      // 14*8*64*8 = 57344 h
    _Float16* PO1 = PB3 + 14 * 8 * 64 * 8;      // 16*7*64*8 = 57344 h
    _Float16* PO2 = PO1 + 16 * 7 * 64 * 8;      // 16*8*64*8 = 65536 h

    precompute_kernel<<<NE + 3 * BB, 256, 0, stream>>>(
        h_abs, e_feat, field, mW1, mb1, oW1, ob1, E1, F1, Fo, S);

    pack_weights<<<480, 64, 0, stream>>>(
        mW2, mW3, oW1, oW2, PB2, PB3, PO1, PO2);

    fused_mfma<<<NBLK, 512, 0, stream>>>(
        h_abs, mb2, mb3, ob2, oW3, ob3,
        E1, F1, Fo, S,
        (const half8*)PB2, (const half8*)PB3, (const half8*)PO1, (const half8*)PO2,
        out);
}

// Round 16
// 97.290 us; speedup vs baseline: 1.0766x; 1.0766x over previous
//
#include <hip/hip_runtime.h>
#include <math.h>

// Problem constants
#define BB 256
#define NE 400
#define NP (BB * NE)        // 102400 pairs
#define HID 256
#define NCOP 224
#define DIN 480
#define MBLK 64             // pairs per block in fused MFMA kernel
#define NBLK (NP / MBLK)    // 1600

typedef _Float16 half8 __attribute__((ext_vector_type(8)));
typedef _Float16 half4 __attribute__((ext_vector_type(4)));
typedef float f4 __attribute__((ext_vector_type(4)));

// Native silu: v_mul + v_exp_f32 + v_add + v_rcp_f32 + v_mul (round 13: -12 us).
static __device__ __forceinline__ float silu_f(float x) {
    float e = __builtin_amdgcn_exp2f(x * -1.44269504088896340736f);
    return x * __builtin_amdgcn_rcpf(1.0f + e);
}

// Swizzled byte offset into the activation LDS buffer.
static __device__ __forceinline__ int swz(int row, int colbyte) {
    return (row * 512 + colbyte) ^ ((row & 7) << 4);
}

// ---------------------------------------------------------------------------
// Precompute (fp32): E1/F1/Fo/S as before.
// ---------------------------------------------------------------------------
__global__ void precompute_kernel(const float* __restrict__ h_abs,
                                  const float* __restrict__ e_feat,
                                  const float* __restrict__ field,
                                  const float* __restrict__ mW1,
                                  const float* __restrict__ mb1,
                                  const float* __restrict__ oW1,
                                  const float* __restrict__ ob1,
                                  float* __restrict__ E1,
                                  float* __restrict__ F1,
                                  float* __restrict__ Fo,
                                  float* __restrict__ S)
{
    int r = blockIdx.x;
    int t = threadIdx.x;
    if (r < NE) {
        float a = 0.f;
        #pragma unroll
        for (int k = 0; k < 32; ++k) a += e_feat[r * 32 + k] * mW1[k * HID + t];
        E1[r * HID + t] = a;
    } else if (r < NE + BB) {
        int b = r - NE;
        float a = mb1[t];
        #pragma unroll
        for (int k = 0; k < 64; ++k) a += field[b * 64 + k] * mW1[(32 + k) * HID + t];
        F1[b * HID + t] = a;
    } else if (r < NE + 2 * BB) {
        int b = r - NE - BB;
        float a = ob1[t];
        #pragma unroll
        for (int k = 0; k < 64; ++k) a += field[b * 64 + k] * oW1[(224 + k) * HID + t];
        Fo[b * HID + t] = a;
    } else {
        int b = r - NE - 2 * BB;
        if (t < 64) {
            const float* x = h_abs + b * DIN + 128 + t * 3;
            S[b * 96 + t] = (x[0]*x[0] + x[1]*x[1] + x[2]*x[2]) * (1.0f / 3.0f);
        } else if (t < 96) {
            int c = t - 64;
            const float* x = h_abs + b * DIN + 320 + c * 5;
            float s = 0.f;
            #pragma unroll
            for (int d = 0; d < 5; ++d) s += x[d] * x[d];
            S[b * 96 + t] = s * 0.2f;
        }
    }
}

// ---------------------------------------------------------------------------
// Pack weights (fp32 -> fp16) into MFMA A-operand fragment order.
// ---------------------------------------------------------------------------
__global__ void pack_weights(const float* __restrict__ mW2, const float* __restrict__ mW3,
                             const float* __restrict__ oW1, const float* __restrict__ oW2,
                             _Float16* __restrict__ PB2, _Float16* __restrict__ PB3,
                             _Float16* __restrict__ PO1, _Float16* __restrict__ PO2)
{
    int blk = blockIdx.x;
    int l = threadIdx.x;
    const float* W; _Float16* P; int LD;
    if (blk < 128)      { W = mW2; P = PB2; LD = 256; }
    else if (blk < 240) { blk -= 128; W = mW3; P = PB3; LD = 224; }
    else if (blk < 352) { blk -= 240; W = oW1; P = PO1; LD = 256; }
    else                { blk -= 352; W = oW2; P = PO2; LD = 256; }
    int KST = (P == PO1) ? 7 : 8;
    int nt = blk / KST, ks = blk - nt * KST;
    int n  = nt * 16 + (l & 15);
    int k0 = ks * 32 + (l >> 4) * 8;
    half8 v;
    #pragma unroll
    for (int j = 0; j < 8; ++j) v[j] = (_Float16)W[(size_t)(k0 + j) * LD + n];
    *(half8*)&P[(size_t)(blk * 64 + l) * 8] = v;
}

// ---------------------------------------------------------------------------
// One GEMM phase on the matrix pipe, operands swapped:
//   acc = mfma(W_frag /*A: rows=n*/, act_frag /*B: cols=pair*/, acc)
// Weight fragments hoisted up-front. Accumulator is CALLER-INITIALIZED
// (bias folded into C-in: the MFMA adds it for free).
// ---------------------------------------------------------------------------
template<int KST, bool TWO>
static __device__ __forceinline__ void mma_phase(const half8* __restrict__ Wp,
                                                 const char* actp, int lane,
                                                 int tile0, f4 acc[4][2])
{
    half8 bf0[KST], bf1[TWO ? KST : 1];
    #pragma unroll
    for (int ks = 0; ks < KST; ++ks)
        bf0[ks] = Wp[(tile0 * KST + ks) * 64 + lane];
    if (TWO) {
        #pragma unroll
        for (int ks = 0; ks < KST; ++ks)
            bf1[ks] = Wp[((tile0 + 8) * KST + ks) * 64 + lane];
    }

    #pragma unroll
    for (int ks = 0; ks < KST; ++ks) {
        int kb = ks * 64 + ((lane >> 4) << 4);
        half8 a[4];
        #pragma unroll
        for (int mt = 0; mt < 4; ++mt) {
            int row = mt * 16 + (lane & 15);
            a[mt] = *(const half8*)(actp + ((row * 512 + kb) ^ ((row & 7) << 4)));
        }
        #pragma unroll
        for (int mt = 0; mt < 4; ++mt)
            acc[mt][0] = __builtin_amdgcn_mfma_f32_16x16x32_f16(bf0[ks], a[mt], acc[mt][0], 0, 0, 0);
        if (TWO) {
            #pragma unroll
            for (int mt = 0; mt < 4; ++mt)
                acc[mt][1] = __builtin_amdgcn_mfma_f32_16x16x32_f16(bf1[ks], a[mt], acc[mt][1], 0, 0, 0);
        }
    }
}

// ---------------------------------------------------------------------------
// Fused kernel: 64 pairs / block, 512 threads (8 waves).
// Single 32 KB act buffer; E+F in-register; all biases preloaded at start and
// folded into accumulator init (MFMA C-operand performs the adds for free).
// ---------------------------------------------------------------------------
__global__ __launch_bounds__(512, 1)
void fused_mfma(const float* __restrict__ h_abs,
                const float* __restrict__ mb2, const float* __restrict__ mb3,
                const float* __restrict__ ob2,
                const float* __restrict__ oW3, const float* __restrict__ ob3,
                const float* __restrict__ E1, const float* __restrict__ F1,
                const float* __restrict__ Fo, const float* __restrict__ S,
                const half8* __restrict__ PB2, const half8* __restrict__ PB3,
                const half8* __restrict__ PO1, const half8* __restrict__ PO2,
                float* __restrict__ out)
{
    __shared__ char act[MBLK * 512];   // 32 KB f16 activations [64][256]
    __shared__ float sred[8][64];      // cross-wave partial sums

    const int t    = threadIdx.x;
    const int lane = t & 63;
    const int w    = t >> 6;           // 0..7
    const int p0   = blockIdx.x * MBLK;
    const int lr   = lane & 15;
    const int lq   = lane >> 4;

    const int b0 = p0 / NE;
    const int r0 = p0 - b0 * NE;

    // Preload all per-column constants once (off the critical path).
    // Column bases: n0 = (w + ntj*8)*16 + lq*4, ntj = 0,1.
    const int nA = w * 16 + lq * 4;          // ntj = 0 (tile w, < 8)
    const int nB = (w + 8) * 16 + lq * 4;    // ntj = 1 (tile w+8)
    f4 bmb2[2], bmb3[2], bob2[2], wv3[2];
    bmb2[0] = *(const f4*)&mb2[nA];  bmb2[1] = *(const f4*)&mb2[nB];
    bmb3[0] = *(const f4*)&mb3[nA];
    bmb3[1] = (w < 6) ? *(const f4*)&mb3[nB] : (f4){0.f, 0.f, 0.f, 0.f};
    bob2[0] = *(const f4*)&ob2[nA];  bob2[1] = *(const f4*)&ob2[nB];
    wv3[0]  = *(const f4*)&oW3[nA];  wv3[1]  = *(const f4*)&oW3[nB];

    // ---- Phase A: h1 = silu(E1[e] + F1[b])  -> act (f16) ----
    {
        #pragma unroll
        for (int i = 0; i < 4; ++i) {
            int c   = i * 512 + t;
            int row = c >> 5;
            int c0  = (c & 31) * 8;
            int e = r0 + row;
            int b = b0;
            if (e >= NE) { e -= NE; b += 1; }
            const f4* ep = (const f4*)&E1[e * HID + c0];
            const f4* fp = (const f4*)&F1[b * HID + c0];
            f4 e0 = ep[0], e1 = ep[1];
            f4 f0 = fp[0], f1 = fp[1];
            half8 hv;
            #pragma unroll
            for (int j = 0; j < 4; ++j) hv[j]     = (_Float16)silu_f(e0[j] + f0[j]);
            #pragma unroll
            for (int j = 0; j < 4; ++j) hv[4 + j] = (_Float16)silu_f(e1[j] + f1[j]);
            *(half8*)(act + swz(row, c0 * 2)) = hv;
        }
    }
    __syncthreads();

    f4 acc[4][2];

    // ---- Phase B: h2 = silu(h1 @ mW2 + mb2)  [in-place, bias-folded] ----
    #pragma unroll
    for (int mt = 0; mt < 4; ++mt) { acc[mt][0] = bmb2[0]; acc[mt][1] = bmb2[1]; }
    mma_phase<8, true>(PB2, act, lane, w, acc);
    __syncthreads();   // all reads of h1 done
    #pragma unroll
    for (int ntj = 0; ntj < 2; ++ntj) {
        int n0 = ntj ? nB : nA;
        #pragma unroll
        for (int mt = 0; mt < 4; ++mt) {
            int row = mt * 16 + lr;
            half4 hv;
            #pragma unroll
            for (int r = 0; r < 4; ++r)
                hv[r] = (_Float16)silu_f(acc[mt][ntj][r]);
            *(half4*)(act + swz(row, n0 * 2)) = hv;
        }
    }
    __syncthreads();   // h2 visible

    // ---- Phase C: g = h2 @ mW3 + mb3 ; invariant  [in-place, bias-folded] ----
    #pragma unroll
    for (int mt = 0; mt < 4; ++mt) { acc[mt][0] = bmb3[0]; acc[mt][1] = bmb3[1]; }
    if (w < 6) mma_phase<8, true >(PB3, act, lane, w, acc);
    else       mma_phase<8, false>(PB3, act, lane, w, acc);
    int bmt[4];
    #pragma unroll
    for (int mt = 0; mt < 4; ++mt)
        bmt[mt] = b0 + ((r0 + mt * 16 + lr) >= NE);
    f4 xh[4], sv[4];
    {
        #pragma unroll
        for (int mt = 0; mt < 4; ++mt)
            xh[mt] = *(const f4*)&h_abs[bmt[mt] * DIN + nA];
        if (w < 6) {
            #pragma unroll
            for (int mt = 0; mt < 4; ++mt)
                sv[mt] = *(const f4*)&S[bmt[mt] * 96 + nA];   // S-index for tile w+8 is nB-128 == nA
        }
    }
    __syncthreads();
    {
        // ntj=0: tile w (<8) -> scalar passthrough path, always.
        #pragma unroll
        for (int mt = 0; mt < 4; ++mt) {
            int row = mt * 16 + lr;
            half4 hv;
            #pragma unroll
            for (int r = 0; r < 4; ++r)
                hv[r] = (_Float16)(xh[mt][r] * acc[mt][0][r]);
            *(half4*)(act + swz(row, nA * 2)) = hv;
        }
        // ntj=1: tile w+8 (>=8, exists iff w<6) -> L2-norm path.
        if (w < 6) {
            #pragma unroll
            for (int mt = 0; mt < 4; ++mt) {
                int row = mt * 16 + lr;
                half4 hv;
                #pragma unroll
                for (int r = 0; r < 4; ++r) {
                    float g = acc[mt][1][r];
                    hv[r] = (_Float16)__builtin_amdgcn_sqrtf(g * g * sv[mt][r] + 1e-8f);
                }
                *(half4*)(act + swz(row, nB * 2)) = hv;
            }
        }
    }
    __syncthreads();

    // ---- Phase D: o1 = silu(inv @ oW1[0:224] + Fo[b])  [in-place, Fo-folded] ----
    #pragma unroll
    for (int mt = 0; mt < 4; ++mt) {
        acc[mt][0] = *(const f4*)&Fo[bmt[mt] * HID + nA];
        acc[mt][1] = *(const f4*)&Fo[bmt[mt] * HID + nB];
    }
    mma_phase<7, true>(PO1, act, lane, w, acc);
    __syncthreads();
    #pragma unroll
    for (int ntj = 0; ntj < 2; ++ntj) {
        int n0 = ntj ? nB : nA;
        #pragma unroll
        for (int mt = 0; mt < 4; ++mt) {
            int row = mt * 16 + lr;
            half4 hv;
            #pragma unroll
            for (int r = 0; r < 4; ++r)
                hv[r] = (_Float16)silu_f(acc[mt][ntj][r]);
            *(half4*)(act + swz(row, n0 * 2)) = hv;
        }
    }
    __syncthreads();

    // ---- Phase E+F fused: out[p] = silu(o1 @ oW2 + ob2) . oW3 + ob3 ----
    #pragma unroll
    for (int mt = 0; mt < 4; ++mt) { acc[mt][0] = bob2[0]; acc[mt][1] = bob2[1]; }
    mma_phase<8, true>(PO2, act, lane, w, acc);
    {
        float partial[4] = {0.f, 0.f, 0.f, 0.f};
        #pragma unroll
        for (int ntj = 0; ntj < 2; ++ntj) {
            #pragma unroll
            for (int mt = 0; mt < 4; ++mt)
                #pragma unroll
                for (int r = 0; r < 4; ++r)
                    partial[mt] += silu_f(acc[mt][ntj][r]) * wv3[ntj][r];
        }
        #pragma unroll
        for (int mt = 0; mt < 4; ++mt) {
            float s = partial[mt];
            s += __shfl_xor(s, 16, 64);
            s += __shfl_xor(s, 32, 64);
            if (lq == 0) sred[w][mt * 16 + lr] = s;
        }
    }
    __syncthreads();
    if (t < 64) {
        float s = ob3[0];
        #pragma unroll
        for (int ww = 0; ww < 8; ++ww) s += sred[ww][t];
        out[p0 + t] = s;
    }
}

extern "C" void kernel_launch(void* const* d_in, const int* in_sizes, int n_in,
                              void* d_out, int out_size, void* d_ws, size_t ws_size,
                              hipStream_t stream) {
    const float* h_abs  = (const float*)d_in[0];
    const float* e_feat = (const float*)d_in[1];
    const float* field  = (const float*)d_in[2];
    const float* mW1 = (const float*)d_in[3];
    const float* mb1 = (const float*)d_in[4];
    const float* mW2 = (const float*)d_in[5];
    const float* mb2 = (const float*)d_in[6];
    const float* mW3 = (const float*)d_in[7];
    const float* mb3 = (const float*)d_in[8];
    const float* oW1 = (const float*)d_in[9];
    const float* ob1 = (const float*)d_in[10];
    const float* oW2 = (const float*)d_in[11];
    const float* ob2 = (const float*)d_in[12];
    const float* oW3 = (const float*)d_in[13];
    const float* ob3 = (const float*)d_in[14];
    float* out = (float*)d_out;

    // Workspace layout
    float* ws = (float*)d_ws;
    float* E1 = ws;                      // 400*256 = 102400 f
    float* F1 = E1 + NE * HID;           // 65536 f
    float* Fo = F1 + BB * HID;           // 65536 f
    float* S  = Fo + BB * HID;           // 24576 f
    _Float16* PB2 = (_Float16*)(S + BB * 96);   // 16*8*64*8 = 65536 h
    _Float16* PB3 = PB2 + 16 * 8 * 64 * 8;      // 14*8*64*8 = 57344 h
    _Float16* PO1 = PB3 + 14 * 8 * 64 * 8;      // 16*7*64*8 = 57344 h
    _Float16* PO2 = PO1 + 16 * 7 * 64 * 8;      // 16*8*64*8 = 65536 h

    precompute_kernel<<<NE + 3 * BB, 256, 0, stream>>>(
        h_abs, e_feat, field, mW1, mb1, oW1, ob1, E1, F1, Fo, S);

    pack_weights<<<480, 64, 0, stream>>>(
        mW2, mW3, oW1, oW2, PB2, PB3, PO1, PO2);

    fused_mfma<<<NBLK, 512, 0, stream>>>(
        h_abs, mb2, mb3, ob2, oW3, ob3,
        E1, F1, Fo, S,
        (const half8*)PB2, (const half8*)PB3, (const half8*)PO1, (const half8*)PO2,
        out);
}